// Round 2
// baseline (2069.478 us; speedup 1.0000x reference)
//
#include <hip/hip_runtime.h>
#include <hip/hip_bf16.h>

#define N_ATOMS 131072
#define N_EDGES 524288
#define N_MOLS  2048
#define DD      128   // n_atom_basis
#define FF      128   // n_filters
#define GG      50    // n_gaussians
#define TT      3

typedef __hip_bfloat16 bf16;
typedef __attribute__((ext_vector_type(8))) short short8;
typedef __attribute__((ext_vector_type(4))) float floatx4;

__device__ __forceinline__ float b2f(bf16 v) { return __bfloat162float(v); }
__device__ __forceinline__ bf16  f2b(float v) { return __float2bfloat16(v); }

// shifted softplus: softplus(x) - ln2, numerically stable
__device__ __forceinline__ float sspf(float x) {
    return fmaxf(x, 0.f) + log1pf(__expf(-fabsf(x))) - 0.69314718056f;
}

// ---------------------------------------------------------------------------
// MFMA helpers.  A tile: [128 rows][136] bf16 LDS (stride 136).
// B tile: [ncols n][72] bf16 LDS (stride 72) holding B^T chunk: B[n][kk], kk<64.
// Each block = 256 threads = 4 waves; wave w owns output rows [32w, 32w+32).
// 16x16x32 bf16 MFMA layouts: A[m=lane&15][k=q*8+j], B[k=q*8+j][n=lane&15],
// D[row=q*4+reg][col=lane&15].  (verified layouts, learn_hip m89)
// ---------------------------------------------------------------------------
template <int NCT>
__device__ __forceinline__ void mfma_half(const bf16* A, const bf16* B,
                                          floatx4 (&acc)[2][NCT],
                                          int kA, int wave, int q, int ln) {
#pragma unroll
    for (int k0 = 0; k0 < 64; k0 += 32) {
        short8 a0 = *(const short8*)(A + (wave * 32 + ln) * 136 + kA + k0 + q * 8);
        short8 a1 = *(const short8*)(A + (wave * 32 + 16 + ln) * 136 + kA + k0 + q * 8);
#pragma unroll
        for (int ct = 0; ct < NCT; ct++) {
            short8 b = *(const short8*)(B + (ct * 16 + ln) * 72 + k0 + q * 8);
            acc[0][ct] = __builtin_amdgcn_mfma_f32_16x16x32_bf16(a0, b, acc[0][ct], 0, 0, 0);
            acc[1][ct] = __builtin_amdgcn_mfma_f32_16x16x32_bf16(a1, b, acc[1][ct], 0, 0, 0);
        }
    }
}

// copy nrows x 64 bf16 (k-half starting at k0) from pre-transposed bf16 weight
// WT (row stride ldk) into LDS B tile, short8 granularity.
__device__ __forceinline__ void stage_b(bf16* B, const bf16* WT, int k0,
                                        int nrows, int ldk, int tid) {
    for (int i = tid; i < nrows * 8; i += 256) {
        int n = i >> 3, kc = i & 7;
        *(short8*)(B + n * 72 + kc * 8) =
            *(const short8*)(WT + n * ldk + k0 + kc * 8);
    }
}

// ---------------------------------------------------------------------------
// r = emb[z]  (fp32 state, exact copy)
__global__ __launch_bounds__(256) void k_init(const float* __restrict__ emb,
                                              const int* __restrict__ z,
                                              float* __restrict__ r) {
    int idx = blockIdx.x * 256 + threadIdx.x;
    int atom = idx >> 7, col = idx & 127;
    r[idx] = emb[z[atom] * DD + col];
}

// per-edge distance + cosine cutoff (exact fp32); also zero molE
__global__ __launch_bounds__(256) void k_dist(const float* __restrict__ xyz,
                                              const int* __restrict__ a,
                                              float* __restrict__ dArr,
                                              float* __restrict__ cArr,
                                              float* __restrict__ molE) {
    int e = blockIdx.x * 256 + threadIdx.x;
    if (e < N_MOLS) molE[e] = 0.f;
    int A0 = a[2 * e], A1 = a[2 * e + 1];
    float dx = xyz[3 * A0]     - xyz[3 * A1];
    float dy = xyz[3 * A0 + 1] - xyz[3 * A1 + 1];
    float dz = xyz[3 * A0 + 2] - xyz[3 * A1 + 2];
    float d = sqrtf(dx * dx + dy * dy + dz * dz);
    dArr[e] = d;
    cArr[e] = 0.5f * (__cosf(d * 0.6283185307179586f) + 1.f);
}

// convert fp32 weights -> bf16, transposed (B^T[n][k]); fw1 zero-padded K 50->64
__global__ __launch_bounds__(256) void k_wt(const float* __restrict__ fw1,
                                            const float* __restrict__ fw2,
                                            const float* __restrict__ win,
                                            const float* __restrict__ wout1,
                                            const float* __restrict__ wout2,
                                            const float* __restrict__ wa1,
                                            bf16* __restrict__ fw1T, bf16* __restrict__ fw2T,
                                            bf16* __restrict__ winT, bf16* __restrict__ wout1T,
                                            bf16* __restrict__ wout2T, bf16* __restrict__ wa1T) {
    int idx = blockIdx.x * 256 + threadIdx.x;
    if (idx < 3 * 128 * 64) {  // fw1T: [t][n<128][k<64]
        int t = idx / 8192, j = idx % 8192;
        int n = j >> 6, k = j & 63;
        fw1T[idx] = (k < GG) ? f2b(fw1[t * GG * FF + k * FF + n]) : f2b(0.f);
        return;
    }
    idx -= 3 * 128 * 64;
    if (idx < 3 * 16384) { int t = idx / 16384, j = idx % 16384; int n = j >> 7, k = j & 127;
        fw2T[idx] = f2b(fw2[t * 16384 + k * 128 + n]); return; }
    idx -= 3 * 16384;
    if (idx < 3 * 16384) { int t = idx / 16384, j = idx % 16384; int n = j >> 7, k = j & 127;
        winT[idx] = f2b(win[t * 16384 + k * 128 + n]); return; }
    idx -= 3 * 16384;
    if (idx < 3 * 16384) { int t = idx / 16384, j = idx % 16384; int n = j >> 7, k = j & 127;
        wout1T[idx] = f2b(wout1[t * 16384 + k * 128 + n]); return; }
    idx -= 3 * 16384;
    if (idx < 3 * 16384) { int t = idx / 16384, j = idx % 16384; int n = j >> 7, k = j & 127;
        wout2T[idx] = f2b(wout2[t * 16384 + k * 128 + n]); return; }
    idx -= 3 * 16384;
    if (idx < 64 * 128) { int n = idx >> 7, k = idx & 127;
        wa1T[idx] = f2b(wa1[k * 64 + n]); return; }
}

// h = bf16(r) @ win[t]   (no bias); also zero y for this iteration
__global__ __launch_bounds__(256) void k_h(const float* __restrict__ r,
                                           const bf16* __restrict__ winT_t,
                                           bf16* __restrict__ h,
                                           float* __restrict__ y) {
    __shared__ __align__(16) bf16 A[128][136];
    __shared__ __align__(16) bf16 B[128][72];
    int tid = threadIdx.x, n0 = blockIdx.x * 128;
    for (int idx = tid; idx < 128 * 128; idx += 256) {
        int row = idx >> 7, col = idx & 127;
        A[row][col] = f2b(r[(n0 + row) * DD + col]);
        y[(n0 + row) * FF + col] = 0.f;
    }
    stage_b(&B[0][0], winT_t, 0, 128, 128, tid);
    __syncthreads();
    int wave = tid >> 6, lane = tid & 63, q = lane >> 4, ln = lane & 15;
    floatx4 acc[2][8];
#pragma unroll
    for (int i = 0; i < 2; i++)
#pragma unroll
        for (int j = 0; j < 8; j++) acc[i][j] = (floatx4){0.f, 0.f, 0.f, 0.f};
    mfma_half<8>(&A[0][0], &B[0][0], acc, 0, wave, q, ln);
    __syncthreads();
    stage_b(&B[0][0], winT_t, 64, 128, 128, tid);
    __syncthreads();
    mfma_half<8>(&A[0][0], &B[0][0], acc, 64, wave, q, ln);
#pragma unroll
    for (int rt = 0; rt < 2; rt++)
#pragma unroll
        for (int ct = 0; ct < 8; ct++)
#pragma unroll
            for (int rg = 0; rg < 4; rg++) {
                int row = wave * 32 + rt * 16 + q * 4 + rg, col = ct * 16 + ln;
                h[(n0 + row) * FF + col] = f2b(acc[rt][ct][rg]);
            }
}

// edge filter W = ssp(g@fw1+b)@fw2+b, W*=C; scatter h[a1]*W -> y[a0], h[a0]*W -> y[a1]
__global__ __launch_bounds__(256) void k_edge(const float* __restrict__ dArr,
                                              const float* __restrict__ cArr,
                                              const int* __restrict__ a,
                                              const bf16* __restrict__ fw1T_t,
                                              const float* __restrict__ fb1_t,
                                              const bf16* __restrict__ fw2T_t,
                                              const float* __restrict__ fb2_t,
                                              const bf16* __restrict__ h,
                                              float* __restrict__ y) {
    __shared__ __align__(16) bf16 A[128][136];
    __shared__ __align__(16) bf16 B[128][72];
    __shared__ float dS[128], cS[128], b1S[128], b2S[128];
    __shared__ int a0S[128], a1S[128];
    int tid = threadIdx.x, e0 = blockIdx.x * 128;
    if (tid < 128) {
        int e = e0 + tid;
        dS[tid] = dArr[e];
        cS[tid] = cArr[e];
        a0S[tid] = a[2 * e];
        a1S[tid] = a[2 * e + 1];
        b1S[tid] = fb1_t[tid];
        b2S[tid] = fb2_t[tid];
    }
    stage_b(&B[0][0], fw1T_t, 0, 128, 64, tid);
    __syncthreads();
    // gaussian smearing tile g -> A[:, 0..63]  (cols 50..63 zero)
    const float width = 5.0f / 49.0f;
    const float coeff = -0.5f / (width * width);
    for (int idx = tid; idx < 128 * 64; idx += 256) {
        int i = idx >> 6, k = idx & 63;
        float v = 0.f;
        if (k < GG) { float t = dS[i] - (float)k * width; v = __expf(coeff * t * t); }
        A[i][k] = f2b(v);
    }
    __syncthreads();
    int wave = tid >> 6, lane = tid & 63, q = lane >> 4, ln = lane & 15;
    floatx4 acc[2][8];
#pragma unroll
    for (int i = 0; i < 2; i++)
#pragma unroll
        for (int j = 0; j < 8; j++) acc[i][j] = (floatx4){0.f, 0.f, 0.f, 0.f};
    mfma_half<8>(&A[0][0], &B[0][0], acc, 0, wave, q, ln);   // K=64 (padded from 50)
    // u = ssp(. + fb1) -> A (own wave rows only: no cross-wave hazard)
#pragma unroll
    for (int rt = 0; rt < 2; rt++)
#pragma unroll
        for (int ct = 0; ct < 8; ct++)
#pragma unroll
            for (int rg = 0; rg < 4; rg++) {
                int row = wave * 32 + rt * 16 + q * 4 + rg, col = ct * 16 + ln;
                A[row][col] = f2b(sspf(acc[rt][ct][rg] + b1S[col]));
            }
    __syncthreads();
    stage_b(&B[0][0], fw2T_t, 0, 128, 128, tid);
    __syncthreads();
#pragma unroll
    for (int i = 0; i < 2; i++)
#pragma unroll
        for (int j = 0; j < 8; j++) acc[i][j] = (floatx4){0.f, 0.f, 0.f, 0.f};
    mfma_half<8>(&A[0][0], &B[0][0], acc, 0, wave, q, ln);
    __syncthreads();
    stage_b(&B[0][0], fw2T_t, 64, 128, 128, tid);
    __syncthreads();
    mfma_half<8>(&A[0][0], &B[0][0], acc, 64, wave, q, ln);
    // scatter
#pragma unroll
    for (int rt = 0; rt < 2; rt++)
#pragma unroll
        for (int ct = 0; ct < 8; ct++)
#pragma unroll
            for (int rg = 0; rg < 4; rg++) {
                int row = wave * 32 + rt * 16 + q * 4 + rg, col = ct * 16 + ln;
                float w = (acc[rt][ct][rg] + b2S[col]) * cS[row];
                int A0 = a0S[row], A1 = a1S[row];
                float h0 = b2f(h[A0 * FF + col]);
                float h1 = b2f(h[A1 * FF + col]);
                atomicAdd(&y[A0 * FF + col], h1 * w);
                atomicAdd(&y[A1 * FF + col], h0 * w);
            }
}

// dr = ssp(y@wout1+b)@wout2+b ; r += dr
__global__ __launch_bounds__(256) void k_node(const float* __restrict__ y,
                                              const bf16* __restrict__ wout1T_t,
                                              const float* __restrict__ bo1_t,
                                              const bf16* __restrict__ wout2T_t,
                                              const float* __restrict__ bo2_t,
                                              float* __restrict__ r) {
    __shared__ __align__(16) bf16 A[128][136];
    __shared__ __align__(16) bf16 B[128][72];
    __shared__ float b1S[128], b2S[128];
    int tid = threadIdx.x, n0 = blockIdx.x * 128;
    if (tid < 128) { b1S[tid] = bo1_t[tid]; b2S[tid] = bo2_t[tid]; }
    for (int idx = tid; idx < 128 * 128; idx += 256) {
        int row = idx >> 7, col = idx & 127;
        A[row][col] = f2b(y[(n0 + row) * FF + col]);
    }
    stage_b(&B[0][0], wout1T_t, 0, 128, 128, tid);
    __syncthreads();
    int wave = tid >> 6, lane = tid & 63, q = lane >> 4, ln = lane & 15;
    floatx4 acc[2][8];
#pragma unroll
    for (int i = 0; i < 2; i++)
#pragma unroll
        for (int j = 0; j < 8; j++) acc[i][j] = (floatx4){0.f, 0.f, 0.f, 0.f};
    mfma_half<8>(&A[0][0], &B[0][0], acc, 0, wave, q, ln);
    __syncthreads();
    stage_b(&B[0][0], wout1T_t, 64, 128, 128, tid);
    __syncthreads();
    mfma_half<8>(&A[0][0], &B[0][0], acc, 64, wave, q, ln);
    // u = ssp(. + bout1) -> A (own rows)
#pragma unroll
    for (int rt = 0; rt < 2; rt++)
#pragma unroll
        for (int ct = 0; ct < 8; ct++)
#pragma unroll
            for (int rg = 0; rg < 4; rg++) {
                int row = wave * 32 + rt * 16 + q * 4 + rg, col = ct * 16 + ln;
                A[row][col] = f2b(sspf(acc[rt][ct][rg] + b1S[col]));
            }
    __syncthreads();
    stage_b(&B[0][0], wout2T_t, 0, 128, 128, tid);
    __syncthreads();
#pragma unroll
    for (int i = 0; i < 2; i++)
#pragma unroll
        for (int j = 0; j < 8; j++) acc[i][j] = (floatx4){0.f, 0.f, 0.f, 0.f};
    mfma_half<8>(&A[0][0], &B[0][0], acc, 0, wave, q, ln);
    __syncthreads();
    stage_b(&B[0][0], wout2T_t, 64, 128, 128, tid);
    __syncthreads();
    mfma_half<8>(&A[0][0], &B[0][0], acc, 64, wave, q, ln);
#pragma unroll
    for (int rt = 0; rt < 2; rt++)
#pragma unroll
        for (int ct = 0; ct < 8; ct++)
#pragma unroll
            for (int rg = 0; rg < 4; rg++) {
                int row = wave * 32 + rt * 16 + q * 4 + rg, col = ct * 16 + ln;
                int off = (n0 + row) * DD + col;
                r[off] += acc[rt][ct][rg] + b2S[col];
            }
}

// energy head: s = ssp(r@wa1+ba1)@wa2+ba2 per atom; atomic into molE
__global__ __launch_bounds__(256) void k_head(const float* __restrict__ r,
                                              const bf16* __restrict__ wa1T,
                                              const float* __restrict__ ba1,
                                              const float* __restrict__ wa2,
                                              const float* __restrict__ ba2,
                                              const int* __restrict__ mol,
                                              float* __restrict__ molE) {
    __shared__ __align__(16) bf16 A[128][136];
    __shared__ __align__(16) bf16 B[64][72];
    __shared__ __align__(16) bf16 U[128][72];
    __shared__ float wa2S[64], ba1S[64];
    int tid = threadIdx.x, n0 = blockIdx.x * 128;
    if (tid < 64) { wa2S[tid] = wa2[tid]; ba1S[tid] = ba1[tid]; }
    for (int idx = tid; idx < 128 * 128; idx += 256) {
        int row = idx >> 7, col = idx & 127;
        A[row][col] = f2b(r[(n0 + row) * DD + col]);
    }
    stage_b(&B[0][0], wa1T, 0, 64, 128, tid);
    __syncthreads();
    int wave = tid >> 6, lane = tid & 63, q = lane >> 4, ln = lane & 15;
    floatx4 acc[2][4];
#pragma unroll
    for (int i = 0; i < 2; i++)
#pragma unroll
        for (int j = 0; j < 4; j++) acc[i][j] = (floatx4){0.f, 0.f, 0.f, 0.f};
    mfma_half<4>(&A[0][0], &B[0][0], acc, 0, wave, q, ln);
    __syncthreads();
    stage_b(&B[0][0], wa1T, 64, 64, 128, tid);
    __syncthreads();
    mfma_half<4>(&A[0][0], &B[0][0], acc, 64, wave, q, ln);
#pragma unroll
    for (int rt = 0; rt < 2; rt++)
#pragma unroll
        for (int ct = 0; ct < 4; ct++)
#pragma unroll
            for (int rg = 0; rg < 4; rg++) {
                int row = wave * 32 + rt * 16 + q * 4 + rg, col = ct * 16 + ln;
                U[row][col] = f2b(acc[rt][ct][rg] + ba1S[col]);
            }
    __syncthreads();
    if (tid < 128) {
        float s = ba2[0];
#pragma unroll
        for (int j = 0; j < 64; j++) s += sspf(b2f(U[tid][j])) * wa2S[j];
        atomicAdd(&molE[mol[n0 + tid]], s);
    }
}

__global__ __launch_bounds__(256) void k_out(const float* __restrict__ molE,
                                             float* __restrict__ out) {
    int i = blockIdx.x * 256 + threadIdx.x;
    out[i] = molE[i];
}

// ---------------------------------------------------------------------------
extern "C" void kernel_launch(void* const* d_in, const int* in_sizes, int n_in,
                              void* d_out, int out_size, void* d_ws, size_t ws_size,
                              hipStream_t stream) {
    const float* xyz   = (const float*)d_in[0];
    const float* emb   = (const float*)d_in[1];
    const float* fw1   = (const float*)d_in[2];
    const float* fb1   = (const float*)d_in[3];
    const float* fw2   = (const float*)d_in[4];
    const float* fb2   = (const float*)d_in[5];
    const float* win   = (const float*)d_in[6];
    const float* wout1 = (const float*)d_in[7];
    const float* bout1 = (const float*)d_in[8];
    const float* wout2 = (const float*)d_in[9];
    const float* bout2 = (const float*)d_in[10];
    const float* wa1   = (const float*)d_in[11];
    const float* ba1   = (const float*)d_in[12];
    const float* wa2   = (const float*)d_in[13];
    const float* ba2   = (const float*)d_in[14];
    const int*  z     = (const int*)d_in[15];
    const int*  a     = (const int*)d_in[16];
    const int*  mol   = (const int*)d_in[17];

    char* ws = (char*)d_ws;
    float* r    = (float*)ws; ws += (size_t)N_ATOMS * DD * 4;
    float* y    = (float*)ws; ws += (size_t)N_ATOMS * FF * 4;
    bf16*  h    = (bf16*) ws; ws += (size_t)N_ATOMS * FF * 2;
    float* dA   = (float*)ws; ws += (size_t)N_EDGES * 4;
    float* cA   = (float*)ws; ws += (size_t)N_EDGES * 4;
    float* molE = (float*)ws; ws += (size_t)N_MOLS * 4;
    bf16*  fw1T   = (bf16*)ws;
    bf16*  fw2T   = fw1T + 3 * 128 * 64;
    bf16*  winT   = fw2T + 3 * 128 * 128;
    bf16*  wout1T = winT + 3 * 128 * 128;
    bf16*  wout2T = wout1T + 3 * 128 * 128;
    bf16*  wa1T   = wout2T + 3 * 128 * 128;

    k_init<<<N_ATOMS * DD / 256, 256, 0, stream>>>(emb, z, r);
    k_dist<<<N_EDGES / 256, 256, 0, stream>>>(xyz, a, dA, cA, molE);
    k_wt<<<896, 256, 0, stream>>>(fw1, fw2, win, wout1, wout2, wa1,
                                  fw1T, fw2T, winT, wout1T, wout2T, wa1T);
    for (int t = 0; t < TT; t++) {
        k_h<<<N_ATOMS / 128, 256, 0, stream>>>(r, winT + t * 16384, h, y);
        k_edge<<<N_EDGES / 128, 256, 0, stream>>>(dA, cA, a,
                                                  fw1T + t * 8192, fb1 + t * FF,
                                                  fw2T + t * 16384, fb2 + t * FF,
                                                  h, y);
        k_node<<<N_ATOMS / 128, 256, 0, stream>>>(y, wout1T + t * 16384, bout1 + t * DD,
                                                  wout2T + t * 16384, bout2 + t * DD, r);
    }
    k_head<<<N_ATOMS / 128, 256, 0, stream>>>(r, wa1T, ba1, wa2, ba2, mol, molE);
    k_out<<<N_MOLS / 256, 256, 0, stream>>>(molE, (float*)d_out);
}